// Round 2
// baseline (404.233 us; speedup 1.0000x reference)
//
#include <hip/hip_runtime.h>
#include <hip/hip_bf16.h>
#include <math.h>

// Problem constants
#define B_   2
#define T_   2048
#define D_   2048
#define NH_  16
#define NKV_ 4
#define HD_  128
#define MROWS (B_*T_)          // 4096
#define NQKV  (NH_*HD_ + 2*NKV_*HD_)  // 3072

typedef __bf16 bf16_t;
typedef __bf16 bf16x8 __attribute__((ext_vector_type(8)));
typedef float  floatx4 __attribute__((ext_vector_type(4)));

// ---------------------------------------------------------------------------
// async global->LDS, 16B per lane. LDS dest must be wave-uniform base + lane*16.
__device__ __forceinline__ void async_copy16(const bf16_t* gsrc, bf16_t* ldst) {
  __builtin_amdgcn_global_load_lds(
      (const __attribute__((address_space(1))) unsigned int*)gsrc,
      (__attribute__((address_space(3))) unsigned int*)ldst, 16, 0, 0);
}

// ---------------------------------------------------------------------------
// cast fp32 -> bf16, 8 elems/thread
__global__ void cast_f32_bf16(const float* __restrict__ src, bf16_t* __restrict__ dst, int n) {
  int i = (blockIdx.x * 256 + threadIdx.x) * 8;
  if (i >= n) return;
  float4 a = *(const float4*)(src + i);
  float4 b = *(const float4*)(src + i + 4);
  bf16x8 v;
  v[0]=(bf16_t)a.x; v[1]=(bf16_t)a.y; v[2]=(bf16_t)a.z; v[3]=(bf16_t)a.w;
  v[4]=(bf16_t)b.x; v[5]=(bf16_t)b.y; v[6]=(bf16_t)b.z; v[7]=(bf16_t)b.w;
  *(bf16x8*)(dst + i) = v;
}

// ---------------------------------------------------------------------------
// transpose + cast: src (K,N) fp32 row-major -> dst (N,K) bf16 row-major
// grid (N/32, K/32), block (32,8)
__global__ void transpose_cast(const float* __restrict__ src, bf16_t* __restrict__ dst,
                               int K, int N) {
  __shared__ float tile[32][33];
  int n0 = blockIdx.x * 32, k0 = blockIdx.y * 32;
  int tx = threadIdx.x, ty = threadIdx.y;
#pragma unroll
  for (int r = 0; r < 4; r++)
    tile[ty + r*8][tx] = src[(size_t)(k0 + ty + r*8) * N + n0 + tx];
  __syncthreads();
#pragma unroll
  for (int r = 0; r < 4; r++)
    dst[(size_t)(n0 + ty + r*8) * K + k0 + tx] = (bf16_t)tile[tx][ty + r*8];
}

// ---------------------------------------------------------------------------
// C(M,N) = A(M,K) * Bt(N,K)^T   all bf16 in, OUT_T out.
// 128x128 tile, BK=64, 4 waves (2x2 of 64x64), 16x16x32 MFMA.
template <typename OUT_T>
__global__ __launch_bounds__(256, 2)
void gemm_bt(const bf16_t* __restrict__ A, const bf16_t* __restrict__ Bt,
             OUT_T* __restrict__ C, int M, int N, int K) {
  __shared__ __align__(16) bf16_t As[128 * 64];
  __shared__ __align__(16) bf16_t Bs[128 * 64];
  const int tid  = threadIdx.x;
  const int wave = tid >> 6, lane = tid & 63;
  const int quad = lane >> 4, l16 = lane & 15;
  const int nBlocksM = M >> 7;
  const int bm = blockIdx.x % nBlocksM, bn = blockIdx.x / nBlocksM;
  const int m0 = bm * 128, n0 = bn * 128;
  const int wm = (wave >> 1) * 64, wn = (wave & 1) * 64;

  floatx4 acc[4][4];
#pragma unroll
  for (int i = 0; i < 4; i++)
#pragma unroll
    for (int j = 0; j < 4; j++) acc[i][j] = floatx4{0.f, 0.f, 0.f, 0.f};

  for (int k0 = 0; k0 < K; k0 += 64) {
    __syncthreads();
#pragma unroll
    for (int i = 0; i < 4; i++) {
      int e = i * 256 + tid;
      int row = e >> 3, grp = e & 7;
      int gg = grp ^ (row & 7);
      async_copy16(A + (size_t)(m0 + row) * K + k0 + gg * 8, As + e * 8);
    }
#pragma unroll
    for (int i = 0; i < 4; i++) {
      int e = i * 256 + tid;
      int row = e >> 3, grp = e & 7;
      int gg = grp ^ (row & 7);
      async_copy16(Bt + (size_t)(n0 + row) * K + k0 + gg * 8, Bs + e * 8);
    }
    __syncthreads();
#pragma unroll
    for (int ks = 0; ks < 2; ks++) {
      bf16x8 af[4], bfr[4];
      int grp = ks * 4 + quad;
#pragma unroll
      for (int mi = 0; mi < 4; mi++) {
        int row = wm + mi * 16 + l16;
        af[mi] = *(const bf16x8*)(As + row * 64 + ((grp ^ (row & 7)) << 3));
      }
#pragma unroll
      for (int ni = 0; ni < 4; ni++) {
        int row = wn + ni * 16 + l16;
        bfr[ni] = *(const bf16x8*)(Bs + row * 64 + ((grp ^ (row & 7)) << 3));
      }
#pragma unroll
      for (int mi = 0; mi < 4; mi++)
#pragma unroll
        for (int ni = 0; ni < 4; ni++)
          acc[mi][ni] = __builtin_amdgcn_mfma_f32_16x16x32_bf16(af[mi], bfr[ni], acc[mi][ni], 0, 0, 0);
    }
  }
  // epilogue: C row = quad*4+reg (+16*mi), col = lane&15 (+16*ni)  [m89/m91 layout]
#pragma unroll
  for (int mi = 0; mi < 4; mi++) {
#pragma unroll
    for (int r = 0; r < 4; r++) {
      int row = m0 + wm + mi * 16 + quad * 4 + r;
      size_t base = (size_t)row * N + n0 + wn;
#pragma unroll
      for (int ni = 0; ni < 4; ni++)
        C[base + ni * 16 + l16] = (OUT_T)acc[mi][ni][r];
    }
  }
}

// ---------------------------------------------------------------------------
// RoPE + scatter: qkv (4096, 3072) bf16 -> Qb (B,NH,T,HD) scaled+roped,
//                 Kb (B,NKV,T,HD) roped.  One thread per (row, head, j<64).
// Q scale = 1/sqrt(128) * log2(e)  (flash softmax runs in exp2 domain)
__global__ void rope_scatter(const bf16_t* __restrict__ qkv,
                             bf16_t* __restrict__ Qb, bf16_t* __restrict__ Kb) {
  int g = blockIdx.x * 256 + threadIdx.x;
  int j = g & 63;
  int rest = g >> 6;
  int head = rest % (NH_ + NKV_);
  int row  = rest / (NH_ + NKV_);     // b*T + t
  int t = row & (T_ - 1);
  int b = row >> 11;                  // T_ = 2048
  const bf16_t* src = qkv + (size_t)row * NQKV;
  // inv_freq = 10000^(-j/64) = exp(-j * ln(10000)/64)
  float ang = (float)t * expf(-0.14391156816f * (float)j);
  float sn, cs;
  sincosf(ang, &sn, &cs);
  if (head < NH_) {
    float x0 = (float)src[head * HD_ + j];
    float x1 = (float)src[head * HD_ + 64 + j];
    const float scale = 0.12751651541057752f;  // 1/sqrt(128)*log2(e)
    bf16_t* dst = Qb + ((size_t)(b * NH_ + head) * T_ + t) * HD_;
    dst[j]      = (bf16_t)((x0 * cs - x1 * sn) * scale);
    dst[j + 64] = (bf16_t)((x1 * cs + x0 * sn) * scale);
  } else {
    int kvh = head - NH_;
    float x0 = (float)src[NH_ * HD_ + kvh * HD_ + j];
    float x1 = (float)src[NH_ * HD_ + kvh * HD_ + 64 + j];
    bf16_t* dst = Kb + ((size_t)(b * NKV_ + kvh) * T_ + t) * HD_;
    dst[j]      = (bf16_t)(x0 * cs - x1 * sn);
    dst[j + 64] = (bf16_t)(x1 * cs + x0 * sn);
  }
}

// ---------------------------------------------------------------------------
// V transpose: qkv V-slice (b,t,kv,d) -> Vt (B,NKV,HD,T)
__global__ void v_transpose(const bf16_t* __restrict__ qkv, bf16_t* __restrict__ Vt) {
  __shared__ float tile[32][33];
  int t0 = blockIdx.x * 32, d0 = blockIdx.y * 32;
  int bk = blockIdx.z;
  int b = bk / NKV_, kvh = bk % NKV_;
  int tx = threadIdx.x, ty = threadIdx.y;
#pragma unroll
  for (int r = 0; r < 4; r++) {
    int t = t0 + ty + r * 8;
    tile[ty + r*8][tx] =
        (float)qkv[(size_t)(b * T_ + t) * NQKV + (NH_ + NKV_) * HD_ + kvh * HD_ + d0 + tx];
  }
  __syncthreads();
#pragma unroll
  for (int r = 0; r < 4; r++) {
    int d = d0 + ty + r * 8;
    Vt[((size_t)(b * NKV_ + kvh) * HD_ + d) * T_ + t0 + tx] = (bf16_t)tile[tx][ty + r*8];
  }
}

// ---------------------------------------------------------------------------
// Flash attention v2: BQ=128 per block (4 waves x 32 q-rows = 2 m-tiles each),
// BK=64 key tiles, HD=128. Q frags in registers. exp2-domain online softmax.
// Heavy-first block order (qt descending) for causal load balance.
__global__ __launch_bounds__(256, 3)
void flash_attn(const bf16_t* __restrict__ Qb, const bf16_t* __restrict__ Kb,
                const bf16_t* __restrict__ Vt, bf16_t* __restrict__ Ob) {
  __shared__ __align__(16) bf16_t Ks[64 * 128];   // (key, d), swizzle grp^(row&15)
  __shared__ __align__(16) bf16_t Vs[128 * 64];   // (d, key), swizzle grp^(row&7)
  __shared__ __align__(16) bf16_t Ps[4][32 * 72]; // wave-private, +8 pad per row

  const int tid = threadIdx.x;
  const int wave = tid >> 6, lane = tid & 63;
  const int quad = lane >> 4, l16 = lane & 15;
  const int nQT = T_ / 128;  // 16
  const int bid = blockIdx.x;
  const int bh = bid % (B_ * NH_);
  const int qt = (nQT - 1) - (bid / (B_ * NH_));   // heavy-first
  const int h = bh % NH_;
  const int b = bh / NH_;
  const int kv = h >> 2;    // GQA: n_rep = 4

  const bf16_t* qbase = Qb + ((size_t)(b * NH_ + h) * T_ + qt * 128) * HD_;
  const bf16_t* kbase = Kb + ((size_t)(b * NKV_ + kv) * T_) * HD_;
  const bf16_t* vbase = Vt + ((size_t)(b * NKV_ + kv) * HD_) * T_;

  // Q fragments: A[m=l16][k=quad*8+j]; mi = m-tile, ks covers k = ks*32..+31
  bf16x8 qf[2][4];
#pragma unroll
  for (int mi = 0; mi < 2; mi++) {
    const bf16_t* qptr = qbase + (wave * 32 + mi * 16 + l16) * HD_;
#pragma unroll
    for (int ks = 0; ks < 4; ks++)
      qf[mi][ks] = *(const bf16x8*)(qptr + ks * 32 + quad * 8);
  }

  floatx4 o[2][8];
#pragma unroll
  for (int mi = 0; mi < 2; mi++)
#pragma unroll
    for (int i = 0; i < 8; i++) o[mi][i] = floatx4{0.f, 0.f, 0.f, 0.f};
  float m_r[2][4], l_r[2][4];
#pragma unroll
  for (int mi = 0; mi < 2; mi++)
#pragma unroll
    for (int r = 0; r < 4; r++) { m_r[mi][r] = -1e30f; l_r[mi][r] = 0.f; }

  const int wrow0 = qt * 128 + wave * 32;  // this wave's first global q-row
  const int nkt = 2 * qt + 2;

  for (int kt = 0; kt < nkt; kt++) {
    __syncthreads();
    // stage K tile (64 keys x 128 d)
#pragma unroll
    for (int i = 0; i < 4; i++) {
      int e = i * 256 + tid;
      int row = e >> 4, grp = e & 15;
      int gg = grp ^ (row & 15);
      async_copy16(kbase + (size_t)(kt * 64 + row) * HD_ + gg * 8, Ks + e * 8);
    }
    // stage V^T tile (128 d x 64 keys)
#pragma unroll
    for (int i = 0; i < 4; i++) {
      int e = i * 256 + tid;
      int row = e >> 3, grp = e & 7;
      int gg = grp ^ (row & 7);
      async_copy16(vbase + (size_t)row * T_ + kt * 64 + gg * 8, Vs + e * 8);
    }
    __syncthreads();

    // wave-level skip: all 32 of this wave's rows above the diagonal
    if (kt * 64 >= wrow0 + 32) continue;  // barriers stay uniform (top of loop)

    // S = Q K^T : per m-tile, 4 n-tiles of 16 keys
    floatx4 s[2][4];
#pragma unroll
    for (int mi = 0; mi < 2; mi++)
#pragma unroll
      for (int nt = 0; nt < 4; nt++) s[mi][nt] = floatx4{0.f, 0.f, 0.f, 0.f};
#pragma unroll
    for (int ks = 0; ks < 4; ks++) {
      int grp = ks * 4 + quad;
#pragma unroll
      for (int nt = 0; nt < 4; nt++) {
        int row = nt * 16 + l16;
        bf16x8 kf = *(const bf16x8*)(Ks + row * 128 + ((grp ^ (row & 15)) << 3));
#pragma unroll
        for (int mi = 0; mi < 2; mi++)
          s[mi][nt] = __builtin_amdgcn_mfma_f32_16x16x32_bf16(qf[mi][ks], kf, s[mi][nt], 0, 0, 0);
      }
    }

    // causal mask (only needed once kt reaches the diagonal band)
    if (kt >= 2 * qt) {
#pragma unroll
      for (int mi = 0; mi < 2; mi++)
#pragma unroll
        for (int nt = 0; nt < 4; nt++)
#pragma unroll
          for (int r = 0; r < 4; r++) {
            int kg = kt * 64 + nt * 16 + l16;
            int qg = wrow0 + mi * 16 + quad * 4 + r;
            if (kg > qg) s[mi][nt][r] = -1e30f;
          }
    }

    // online softmax (exp2 domain; scale folded into Q)
#pragma unroll
    for (int mi = 0; mi < 2; mi++)
#pragma unroll
      for (int r = 0; r < 4; r++) {
        float mx = fmaxf(fmaxf(s[mi][0][r], s[mi][1][r]), fmaxf(s[mi][2][r], s[mi][3][r]));
#pragma unroll
        for (int off = 1; off < 16; off <<= 1)
          mx = fmaxf(mx, __shfl_xor(mx, off, 64));
        float mnew = fmaxf(m_r[mi][r], mx);
        float alpha = __builtin_amdgcn_exp2f(m_r[mi][r] - mnew);
        m_r[mi][r] = mnew;
        float sum = 0.f;
#pragma unroll
        for (int nt = 0; nt < 4; nt++) {
          float p = __builtin_amdgcn_exp2f(s[mi][nt][r] - mnew);
          s[mi][nt][r] = p;
          sum += p;
        }
#pragma unroll
        for (int off = 1; off < 16; off <<= 1)
          sum += __shfl_xor(sum, off, 64);
        l_r[mi][r] = l_r[mi][r] * alpha + sum;
#pragma unroll
        for (int nto = 0; nto < 8; nto++) o[mi][nto][r] *= alpha;
      }

    // P: C-layout -> A-layout via wave-private LDS (stride 72 => benign conflicts)
#pragma unroll
    for (int mi = 0; mi < 2; mi++)
#pragma unroll
      for (int nt = 0; nt < 4; nt++)
#pragma unroll
        for (int r = 0; r < 4; r++)
          Ps[wave][(mi * 16 + quad * 4 + r) * 72 + nt * 16 + l16] = (bf16_t)s[mi][nt][r];

    // O += P V  (8 n-tiles over d=128; vf reused across both m-tiles)
#pragma unroll
    for (int ks = 0; ks < 2; ks++) {
      bf16x8 pf[2];
#pragma unroll
      for (int mi = 0; mi < 2; mi++)
        pf[mi] = *(const bf16x8*)(&Ps[wave][(mi * 16 + l16) * 72 + ks * 32 + quad * 8]);
      int grp = ks * 4 + quad;
#pragma unroll
      for (int nt = 0; nt < 8; nt++) {
        int row = nt * 16 + l16;
        bf16x8 vf = *(const bf16x8*)(Vs + row * 64 + ((grp ^ (row & 7)) << 3));
#pragma unroll
        for (int mi = 0; mi < 2; mi++)
          o[mi][nt] = __builtin_amdgcn_mfma_f32_16x16x32_bf16(pf[mi], vf, o[mi][nt], 0, 0, 0);
      }
    }
  }

  // epilogue: write (b, t, h*128 + d) bf16
#pragma unroll
  for (int mi = 0; mi < 2; mi++)
#pragma unroll
    for (int r = 0; r < 4; r++) {
      int qg = wrow0 + mi * 16 + quad * 4 + r;
      float inv_l = 1.f / l_r[mi][r];
      size_t base = ((size_t)(b * T_) + qg) * D_ + h * HD_;
#pragma unroll
      for (int nt = 0; nt < 8; nt++)
        Ob[base + nt * 16 + l16] = (bf16_t)(o[mi][nt][r] * inv_l);
    }
}

// ---------------------------------------------------------------------------
extern "C" void kernel_launch(void* const* d_in, const int* in_sizes, int n_in,
                              void* d_out, int out_size, void* d_ws, size_t ws_size,
                              hipStream_t stream) {
  const float* x  = (const float*)d_in[0];
  const float* wq = (const float*)d_in[1];
  const float* wk = (const float*)d_in[2];
  const float* wv = (const float*)d_in[3];
  const float* wo = (const float*)d_in[4];
  float* out = (float*)d_out;

  // workspace layout (bf16 elems); attn output aliases x_bf (x_bf dead after GEMM1)
  bf16_t* x_bf   = (bf16_t*)d_ws;                          // 4096*2048
  bf16_t* attn_o = x_bf;                                   // alias
  bf16_t* wqkv_t = x_bf + (size_t)MROWS * D_;              // 3072*2048
  bf16_t* wo_t   = wqkv_t + (size_t)NQKV * D_;             // 2048*2048
  bf16_t* qkv    = wo_t + (size_t)D_ * D_;                 // 4096*3072
  bf16_t* Qb     = qkv + (size_t)MROWS * NQKV;             // 2*16*2048*128
  bf16_t* Kb     = Qb + (size_t)B_ * NH_ * T_ * HD_;       // 2*4*2048*128
  bf16_t* Vt     = Kb + (size_t)B_ * NKV_ * T_ * HD_;      // 2*4*128*2048

  // 1. casts / weight transposes
  cast_f32_bf16<<<(MROWS * D_) / (256 * 8), 256, 0, stream>>>(x, x_bf, MROWS * D_);
  transpose_cast<<<dim3(64, 64), dim3(32, 8), 0, stream>>>(wq, wqkv_t, D_, 2048);
  transpose_cast<<<dim3(16, 64), dim3(32, 8), 0, stream>>>(wk, wqkv_t + (size_t)2048 * D_, D_, 512);
  transpose_cast<<<dim3(16, 64), dim3(32, 8), 0, stream>>>(wv, wqkv_t + (size_t)2560 * D_, D_, 512);
  transpose_cast<<<dim3(64, 64), dim3(32, 8), 0, stream>>>(wo, wo_t, D_, 2048);

  // 2. fused QKV projection: (4096,2048) x (2048,3072) -> bf16
  gemm_bt<bf16_t><<<(MROWS / 128) * (NQKV / 128), 256, 0, stream>>>(
      x_bf, wqkv_t, qkv, MROWS, NQKV, D_);

  // 3. RoPE + GQA scatter + V transpose
  rope_scatter<<<(MROWS * (NH_ + NKV_) * 64) / 256, 256, 0, stream>>>(qkv, Qb, Kb);
  v_transpose<<<dim3(T_ / 32, HD_ / 32, B_ * NKV_), dim3(32, 8), 0, stream>>>(qkv, Vt);

  // 4. causal flash attention: BQ=128, heavy-first
  flash_attn<<<B_ * NH_ * (T_ / 128), 256, 0, stream>>>(Qb, Kb, Vt, attn_o);

  // 5. output projection: (4096,2048) x (2048,2048) -> fp32
  gemm_bt<float><<<(MROWS / 128) * (D_ / 128), 256, 0, stream>>>(
      attn_o, wo_t, out, MROWS, D_, D_);
}

// Round 3
// 311.697 us; speedup vs baseline: 1.2969x; 1.2969x over previous
//
#include <hip/hip_runtime.h>
#include <hip/hip_bf16.h>
#include <math.h>

// Problem constants
#define B_   2
#define T_   2048
#define D_   2048
#define NH_  16
#define NKV_ 4
#define HD_  128
#define MROWS (B_*T_)          // 4096
#define NQKV  (NH_*HD_ + 2*NKV_*HD_)  // 3072

typedef __bf16 bf16_t;
typedef __bf16 bf16x8 __attribute__((ext_vector_type(8)));
typedef float  floatx4 __attribute__((ext_vector_type(4)));

// ---------------------------------------------------------------------------
// async global->LDS, 16B per lane. LDS dest must be wave-uniform base + lane*16.
__device__ __forceinline__ void async_copy16(const bf16_t* gsrc, bf16_t* ldst) {
  __builtin_amdgcn_global_load_lds(
      (const __attribute__((address_space(1))) unsigned int*)gsrc,
      (__attribute__((address_space(3))) unsigned int*)ldst, 16, 0, 0);
}

// ---------------------------------------------------------------------------
// cast fp32 -> bf16, 8 elems/thread
__global__ void cast_f32_bf16(const float* __restrict__ src, bf16_t* __restrict__ dst, int n) {
  int i = (blockIdx.x * 256 + threadIdx.x) * 8;
  if (i >= n) return;
  float4 a = *(const float4*)(src + i);
  float4 b = *(const float4*)(src + i + 4);
  bf16x8 v;
  v[0]=(bf16_t)a.x; v[1]=(bf16_t)a.y; v[2]=(bf16_t)a.z; v[3]=(bf16_t)a.w;
  v[4]=(bf16_t)b.x; v[5]=(bf16_t)b.y; v[6]=(bf16_t)b.z; v[7]=(bf16_t)b.w;
  *(bf16x8*)(dst + i) = v;
}

// ---------------------------------------------------------------------------
// transpose + cast: src (K,N) fp32 row-major -> dst (N,K) bf16 row-major
// grid (N/32, K/32), block (32,8)
__global__ void transpose_cast(const float* __restrict__ src, bf16_t* __restrict__ dst,
                               int K, int N) {
  __shared__ float tile[32][33];
  int n0 = blockIdx.x * 32, k0 = blockIdx.y * 32;
  int tx = threadIdx.x, ty = threadIdx.y;
#pragma unroll
  for (int r = 0; r < 4; r++)
    tile[ty + r*8][tx] = src[(size_t)(k0 + ty + r*8) * N + n0 + tx];
  __syncthreads();
#pragma unroll
  for (int r = 0; r < 4; r++)
    dst[(size_t)(n0 + ty + r*8) * K + k0 + tx] = (bf16_t)tile[tx][ty + r*8];
}

// ---------------------------------------------------------------------------
// C(M,N) = A(M,K) * Bt(N,K)^T   all bf16 in, OUT_T out.
// 128x128 tile, BK=64, 4 waves (2x2 of 64x64), 16x16x32 MFMA.
template <typename OUT_T>
__global__ __launch_bounds__(256, 2)
void gemm_bt(const bf16_t* __restrict__ A, const bf16_t* __restrict__ Bt,
             OUT_T* __restrict__ C, int M, int N, int K) {
  __shared__ __align__(16) bf16_t As[128 * 64];
  __shared__ __align__(16) bf16_t Bs[128 * 64];
  const int tid  = threadIdx.x;
  const int wave = tid >> 6, lane = tid & 63;
  const int quad = lane >> 4, l16 = lane & 15;
  const int nBlocksM = M >> 7;
  const int bm = blockIdx.x % nBlocksM, bn = blockIdx.x / nBlocksM;
  const int m0 = bm * 128, n0 = bn * 128;
  const int wm = (wave >> 1) * 64, wn = (wave & 1) * 64;

  floatx4 acc[4][4];
#pragma unroll
  for (int i = 0; i < 4; i++)
#pragma unroll
    for (int j = 0; j < 4; j++) acc[i][j] = floatx4{0.f, 0.f, 0.f, 0.f};

  for (int k0 = 0; k0 < K; k0 += 64) {
    __syncthreads();
#pragma unroll
    for (int i = 0; i < 4; i++) {
      int e = i * 256 + tid;
      int row = e >> 3, grp = e & 7;
      int gg = grp ^ (row & 7);
      async_copy16(A + (size_t)(m0 + row) * K + k0 + gg * 8, As + e * 8);
    }
#pragma unroll
    for (int i = 0; i < 4; i++) {
      int e = i * 256 + tid;
      int row = e >> 3, grp = e & 7;
      int gg = grp ^ (row & 7);
      async_copy16(Bt + (size_t)(n0 + row) * K + k0 + gg * 8, Bs + e * 8);
    }
    __syncthreads();
#pragma unroll
    for (int ks = 0; ks < 2; ks++) {
      bf16x8 af[4], bfr[4];
      int grp = ks * 4 + quad;
#pragma unroll
      for (int mi = 0; mi < 4; mi++) {
        int row = wm + mi * 16 + l16;
        af[mi] = *(const bf16x8*)(As + row * 64 + ((grp ^ (row & 7)) << 3));
      }
#pragma unroll
      for (int ni = 0; ni < 4; ni++) {
        int row = wn + ni * 16 + l16;
        bfr[ni] = *(const bf16x8*)(Bs + row * 64 + ((grp ^ (row & 7)) << 3));
      }
#pragma unroll
      for (int mi = 0; mi < 4; mi++)
#pragma unroll
        for (int ni = 0; ni < 4; ni++)
          acc[mi][ni] = __builtin_amdgcn_mfma_f32_16x16x32_bf16(af[mi], bfr[ni], acc[mi][ni], 0, 0, 0);
    }
  }
  // epilogue: C row = quad*4+reg (+16*mi), col = lane&15 (+16*ni)  [m89/m91 layout]
#pragma unroll
  for (int mi = 0; mi < 4; mi++) {
#pragma unroll
    for (int r = 0; r < 4; r++) {
      int row = m0 + wm + mi * 16 + quad * 4 + r;
      size_t base = (size_t)row * N + n0 + wn;
#pragma unroll
      for (int ni = 0; ni < 4; ni++)
        C[base + ni * 16 + l16] = (OUT_T)acc[mi][ni][r];
    }
  }
}

// ---------------------------------------------------------------------------
// RoPE + scatter: qkv (4096, 3072) bf16 -> Qb (B,NH,T,HD) scaled+roped,
//                 Kb (B,NKV,T,HD) roped.  One thread per (row, head, j<64).
// Q scale = 1/sqrt(128) * log2(e)  (flash softmax runs in exp2 domain)
__global__ void rope_scatter(const bf16_t* __restrict__ qkv,
                             bf16_t* __restrict__ Qb, bf16_t* __restrict__ Kb) {
  int g = blockIdx.x * 256 + threadIdx.x;
  int j = g & 63;
  int rest = g >> 6;
  int head = rest % (NH_ + NKV_);
  int row  = rest / (NH_ + NKV_);     // b*T + t
  int t = row & (T_ - 1);
  int b = row >> 11;                  // T_ = 2048
  const bf16_t* src = qkv + (size_t)row * NQKV;
  // inv_freq = 10000^(-j/64) = exp(-j * ln(10000)/64)
  float ang = (float)t * expf(-0.14391156816f * (float)j);
  float sn, cs;
  sincosf(ang, &sn, &cs);
  if (head < NH_) {
    float x0 = (float)src[head * HD_ + j];
    float x1 = (float)src[head * HD_ + 64 + j];
    const float scale = 0.12751651541057752f;  // 1/sqrt(128)*log2(e)
    bf16_t* dst = Qb + ((size_t)(b * NH_ + head) * T_ + t) * HD_;
    dst[j]      = (bf16_t)((x0 * cs - x1 * sn) * scale);
    dst[j + 64] = (bf16_t)((x1 * cs + x0 * sn) * scale);
  } else {
    int kvh = head - NH_;
    float x0 = (float)src[NH_ * HD_ + kvh * HD_ + j];
    float x1 = (float)src[NH_ * HD_ + kvh * HD_ + 64 + j];
    bf16_t* dst = Kb + ((size_t)(b * NKV_ + kvh) * T_ + t) * HD_;
    dst[j]      = (bf16_t)(x0 * cs - x1 * sn);
    dst[j + 64] = (bf16_t)(x1 * cs + x0 * sn);
  }
}

// ---------------------------------------------------------------------------
// V transpose: qkv V-slice (b,t,kv,d) -> Vt (B,NKV,HD,T)
__global__ void v_transpose(const bf16_t* __restrict__ qkv, bf16_t* __restrict__ Vt) {
  __shared__ float tile[32][33];
  int t0 = blockIdx.x * 32, d0 = blockIdx.y * 32;
  int bk = blockIdx.z;
  int b = bk / NKV_, kvh = bk % NKV_;
  int tx = threadIdx.x, ty = threadIdx.y;
#pragma unroll
  for (int r = 0; r < 4; r++) {
    int t = t0 + ty + r * 8;
    tile[ty + r*8][tx] =
        (float)qkv[(size_t)(b * T_ + t) * NQKV + (NH_ + NKV_) * HD_ + kvh * HD_ + d0 + tx];
  }
  __syncthreads();
#pragma unroll
  for (int r = 0; r < 4; r++) {
    int d = d0 + ty + r * 8;
    Vt[((size_t)(b * NKV_ + kvh) * HD_ + d) * T_ + t0 + tx] = (bf16_t)tile[tx][ty + r*8];
  }
}

// ---------------------------------------------------------------------------
// Flash attention v3: BQ=64 per block (4 waves x 16 q-rows), BK=64 key tiles,
// HD=128. DOUBLE-BUFFERED K/V LDS staging: tile kt+1 is issued before
// compute(kt), so the vmcnt(0) drain at the next barrier finds it already
// complete -> staging latency leaves the critical path. One barrier/iter.
// exp2-domain online softmax (scale*log2e folded into Q). Heavy-first order.
__global__ __launch_bounds__(256, 2)
void flash_attn(const bf16_t* __restrict__ Qb, const bf16_t* __restrict__ Kb,
                const bf16_t* __restrict__ Vt, bf16_t* __restrict__ Ob) {
  __shared__ __align__(16) bf16_t Ks[2][64 * 128];   // (key, d), swizzle grp^(row&15)
  __shared__ __align__(16) bf16_t Vs[2][128 * 64];   // (d, key), swizzle grp^(row&7)
  __shared__ __align__(16) bf16_t Ps[4][16 * 72];    // wave-private, +8 pad per row

  const int tid = threadIdx.x;
  const int wave = tid >> 6, lane = tid & 63;
  const int quad = lane >> 4, l16 = lane & 15;
  const int nQT = T_ / 64;  // 32
  const int bid = blockIdx.x;
  const int bh = bid % (B_ * NH_);
  const int qt = (nQT - 1) - (bid / (B_ * NH_));   // heavy-first
  const int h = bh % NH_;
  const int b = bh / NH_;
  const int kv = h >> 2;    // GQA: n_rep = 4

  const bf16_t* qbase = Qb + ((size_t)(b * NH_ + h) * T_ + qt * 64) * HD_;
  const bf16_t* kbase = Kb + ((size_t)(b * NKV_ + kv) * T_) * HD_;
  const bf16_t* vbase = Vt + ((size_t)(b * NKV_ + kv) * HD_) * T_;

  // stage key tile kt into buffer bufi (K: 64 keys x 128 d; V^T: 128 d x 64 keys)
  auto stage = [&](int kt, int bufi) {
#pragma unroll
    for (int i = 0; i < 4; i++) {
      int e = i * 256 + tid;
      int row = e >> 4, grp = e & 15;
      int gg = grp ^ (row & 15);
      async_copy16(kbase + (size_t)(kt * 64 + row) * HD_ + gg * 8, &Ks[bufi][e * 8]);
    }
#pragma unroll
    for (int i = 0; i < 4; i++) {
      int e = i * 256 + tid;
      int row = e >> 3, grp = e & 7;
      int gg = grp ^ (row & 7);
      async_copy16(vbase + (size_t)row * T_ + kt * 64 + gg * 8, &Vs[bufi][e * 8]);
    }
  };

  stage(0, 0);  // prefetch first tile before anything else

  // Q fragments: A[m=l16][k=quad*8+j], k-step ks covers k = ks*32..+31
  bf16x8 qf[4];
  {
    const bf16_t* qptr = qbase + (wave * 16 + l16) * HD_;
#pragma unroll
    for (int ks = 0; ks < 4; ks++)
      qf[ks] = *(const bf16x8*)(qptr + ks * 32 + quad * 8);
  }

  floatx4 o[8];
#pragma unroll
  for (int i = 0; i < 8; i++) o[i] = floatx4{0.f, 0.f, 0.f, 0.f};
  float m_r[4], l_r[4];
#pragma unroll
  for (int r = 0; r < 4; r++) { m_r[r] = -1e30f; l_r[r] = 0.f; }

  for (int kt = 0; kt <= qt; kt++) {
    const int bufi = kt & 1;
    // barrier: (a) drains vmcnt -> staging of THIS tile (issued last iter) done;
    // (b) all waves finished compute on the buffer we are about to overwrite.
    __syncthreads();
    if (kt < qt) stage(kt + 1, bufi ^ 1);  // prefetch next tile (other buffer)

    // S = Q K^T : 4 n-tiles of 16 keys
    floatx4 s[4];
#pragma unroll
    for (int nt = 0; nt < 4; nt++) s[nt] = floatx4{0.f, 0.f, 0.f, 0.f};
#pragma unroll
    for (int ks = 0; ks < 4; ks++) {
      int grp = ks * 4 + quad;
#pragma unroll
      for (int nt = 0; nt < 4; nt++) {
        int row = nt * 16 + l16;
        bf16x8 kf = *(const bf16x8*)(&Ks[bufi][row * 128 + ((grp ^ (row & 15)) << 3)]);
        s[nt] = __builtin_amdgcn_mfma_f32_16x16x32_bf16(qf[ks], kf, s[nt], 0, 0, 0);
      }
    }

    // causal mask (only the diagonal tile needs it)
    if (kt == qt) {
#pragma unroll
      for (int nt = 0; nt < 4; nt++)
#pragma unroll
        for (int r = 0; r < 4; r++) {
          int kg = nt * 16 + l16;
          int qg = wave * 16 + quad * 4 + r;
          if (kg > qg) s[nt][r] = -1e30f;
        }
    }

    // online softmax per q-row, exp2 domain (scale folded into Q)
#pragma unroll
    for (int r = 0; r < 4; r++) {
      float mx = fmaxf(fmaxf(s[0][r], s[1][r]), fmaxf(s[2][r], s[3][r]));
#pragma unroll
      for (int off = 1; off < 16; off <<= 1)
        mx = fmaxf(mx, __shfl_xor(mx, off, 64));
      float mnew = fmaxf(m_r[r], mx);
      float alpha = __builtin_amdgcn_exp2f(m_r[r] - mnew);
      m_r[r] = mnew;
      float sum = 0.f;
#pragma unroll
      for (int nt = 0; nt < 4; nt++) {
        float p = __builtin_amdgcn_exp2f(s[nt][r] - mnew);
        s[nt][r] = p;
        sum += p;
      }
#pragma unroll
      for (int off = 1; off < 16; off <<= 1)
        sum += __shfl_xor(sum, off, 64);
      l_r[r] = l_r[r] * alpha + sum;
#pragma unroll
      for (int nto = 0; nto < 8; nto++) o[nto][r] *= alpha;
    }

    // P: C-layout -> A-layout via wave-private LDS (stride 72 => benign conflicts)
#pragma unroll
    for (int nt = 0; nt < 4; nt++)
#pragma unroll
      for (int r = 0; r < 4; r++)
        Ps[wave][(quad * 4 + r) * 72 + nt * 16 + l16] = (bf16_t)s[nt][r];

    // O += P V  (8 n-tiles over d=128)
#pragma unroll
    for (int ks = 0; ks < 2; ks++) {
      bf16x8 pf = *(const bf16x8*)(&Ps[wave][l16 * 72 + ks * 32 + quad * 8]);
      int grp = ks * 4 + quad;
#pragma unroll
      for (int nt = 0; nt < 8; nt++) {
        int row = nt * 16 + l16;
        bf16x8 vf = *(const bf16x8*)(&Vs[bufi][row * 64 + ((grp ^ (row & 7)) << 3)]);
        o[nt] = __builtin_amdgcn_mfma_f32_16x16x32_bf16(pf, vf, o[nt], 0, 0, 0);
      }
    }
  }

  // epilogue: write (b, t, h*128 + d) bf16
#pragma unroll
  for (int r = 0; r < 4; r++) {
    int qg = qt * 64 + wave * 16 + quad * 4 + r;
    float inv_l = 1.f / l_r[r];
    size_t base = ((size_t)(b * T_) + qg) * D_ + h * HD_;
#pragma unroll
    for (int nt = 0; nt < 8; nt++)
      Ob[base + nt * 16 + l16] = (bf16_t)(o[nt][r] * inv_l);
  }
}

// ---------------------------------------------------------------------------
extern "C" void kernel_launch(void* const* d_in, const int* in_sizes, int n_in,
                              void* d_out, int out_size, void* d_ws, size_t ws_size,
                              hipStream_t stream) {
  const float* x  = (const float*)d_in[0];
  const float* wq = (const float*)d_in[1];
  const float* wk = (const float*)d_in[2];
  const float* wv = (const float*)d_in[3];
  const float* wo = (const float*)d_in[4];
  float* out = (float*)d_out;

  // workspace layout (bf16 elems); attn output aliases x_bf (x_bf dead after GEMM1)
  bf16_t* x_bf   = (bf16_t*)d_ws;                          // 4096*2048
  bf16_t* attn_o = x_bf;                                   // alias
  bf16_t* wqkv_t = x_bf + (size_t)MROWS * D_;              // 3072*2048
  bf16_t* wo_t   = wqkv_t + (size_t)NQKV * D_;             // 2048*2048
  bf16_t* qkv    = wo_t + (size_t)D_ * D_;                 // 4096*3072
  bf16_t* Qb     = qkv + (size_t)MROWS * NQKV;             // 2*16*2048*128
  bf16_t* Kb     = Qb + (size_t)B_ * NH_ * T_ * HD_;       // 2*4*2048*128
  bf16_t* Vt     = Kb + (size_t)B_ * NKV_ * T_ * HD_;      // 2*4*128*2048

  // 1. casts / weight transposes
  cast_f32_bf16<<<(MROWS * D_) / (256 * 8), 256, 0, stream>>>(x, x_bf, MROWS * D_);
  transpose_cast<<<dim3(64, 64), dim3(32, 8), 0, stream>>>(wq, wqkv_t, D_, 2048);
  transpose_cast<<<dim3(16, 64), dim3(32, 8), 0, stream>>>(wk, wqkv_t + (size_t)2048 * D_, D_, 512);
  transpose_cast<<<dim3(16, 64), dim3(32, 8), 0, stream>>>(wv, wqkv_t + (size_t)2560 * D_, D_, 512);
  transpose_cast<<<dim3(64, 64), dim3(32, 8), 0, stream>>>(wo, wo_t, D_, 2048);

  // 2. fused QKV projection: (4096,2048) x (2048,3072) -> bf16
  gemm_bt<bf16_t><<<(MROWS / 128) * (NQKV / 128), 256, 0, stream>>>(
      x_bf, wqkv_t, qkv, MROWS, NQKV, D_);

  // 3. RoPE + GQA scatter + V transpose
  rope_scatter<<<(MROWS * (NH_ + NKV_) * 64) / 256, 256, 0, stream>>>(qkv, Qb, Kb);
  v_transpose<<<dim3(T_ / 32, HD_ / 32, B_ * NKV_), dim3(32, 8), 0, stream>>>(qkv, Vt);

  // 4. causal flash attention: BQ=64, double-buffered staging, heavy-first
  flash_attn<<<B_ * NH_ * (T_ / 64), 256, 0, stream>>>(Qb, Kb, Vt, attn_o);

  // 5. output projection: (4096,2048) x (2048,2048) -> fp32
  gemm_bt<float><<<(MROWS / 128) * (D_ / 128), 256, 0, stream>>>(
      attn_o, wo_t, out, MROWS, D_, D_);
}

// Round 4
// 280.535 us; speedup vs baseline: 1.4409x; 1.1111x over previous
//
#include <hip/hip_runtime.h>
#include <hip/hip_bf16.h>
#include <math.h>

// Problem constants
#define B_   2
#define T_   2048
#define D_   2048
#define NH_  16
#define NKV_ 4
#define HD_  128
#define MROWS (B_*T_)          // 4096
#define NQKV  (NH_*HD_ + 2*NKV_*HD_)  // 3072

typedef __bf16 bf16_t;
typedef __bf16 bf16x8 __attribute__((ext_vector_type(8)));
typedef __bf16 bf16x4 __attribute__((ext_vector_type(4)));
typedef float  floatx4 __attribute__((ext_vector_type(4)));

// ---------------------------------------------------------------------------
// async global->LDS, 16B per lane. LDS dest must be wave-uniform base + lane*16.
__device__ __forceinline__ void async_copy16(const bf16_t* gsrc, bf16_t* ldst) {
  __builtin_amdgcn_global_load_lds(
      (const __attribute__((address_space(1))) unsigned int*)gsrc,
      (__attribute__((address_space(3))) unsigned int*)ldst, 16, 0, 0);
}

// ---------------------------------------------------------------------------
// cast fp32 -> bf16, 8 elems/thread
__global__ void cast_f32_bf16(const float* __restrict__ src, bf16_t* __restrict__ dst, int n) {
  int i = (blockIdx.x * 256 + threadIdx.x) * 8;
  if (i >= n) return;
  float4 a = *(const float4*)(src + i);
  float4 b = *(const float4*)(src + i + 4);
  bf16x8 v;
  v[0]=(bf16_t)a.x; v[1]=(bf16_t)a.y; v[2]=(bf16_t)a.z; v[3]=(bf16_t)a.w;
  v[4]=(bf16_t)b.x; v[5]=(bf16_t)b.y; v[6]=(bf16_t)b.z; v[7]=(bf16_t)b.w;
  *(bf16x8*)(dst + i) = v;
}

// ---------------------------------------------------------------------------
// transpose + cast: src (K,N) fp32 row-major -> dst (N,K) bf16 row-major
// grid (N/32, K/32), block (32,8)
__global__ void transpose_cast(const float* __restrict__ src, bf16_t* __restrict__ dst,
                               int K, int N) {
  __shared__ float tile[32][33];
  int n0 = blockIdx.x * 32, k0 = blockIdx.y * 32;
  int tx = threadIdx.x, ty = threadIdx.y;
#pragma unroll
  for (int r = 0; r < 4; r++)
    tile[ty + r*8][tx] = src[(size_t)(k0 + ty + r*8) * N + n0 + tx];
  __syncthreads();
#pragma unroll
  for (int r = 0; r < 4; r++)
    dst[(size_t)(n0 + ty + r*8) * K + k0 + tx] = (bf16_t)tile[tx][ty + r*8];
}

// ---------------------------------------------------------------------------
// C(M,N) = A(M,K) * Bt(N,K)^T   all bf16 in, OUT_T out.
// 128x128 tile, BK=64, 4 waves (2x2 of 64x64), 16x16x32 MFMA.
template <typename OUT_T>
__global__ __launch_bounds__(256, 2)
void gemm_bt(const bf16_t* __restrict__ A, const bf16_t* __restrict__ Bt,
             OUT_T* __restrict__ C, int M, int N, int K) {
  __shared__ __align__(16) bf16_t As[128 * 64];
  __shared__ __align__(16) bf16_t Bs[128 * 64];
  const int tid  = threadIdx.x;
  const int wave = tid >> 6, lane = tid & 63;
  const int quad = lane >> 4, l16 = lane & 15;
  const int nBlocksM = M >> 7;
  const int bm = blockIdx.x % nBlocksM, bn = blockIdx.x / nBlocksM;
  const int m0 = bm * 128, n0 = bn * 128;
  const int wm = (wave >> 1) * 64, wn = (wave & 1) * 64;

  floatx4 acc[4][4];
#pragma unroll
  for (int i = 0; i < 4; i++)
#pragma unroll
    for (int j = 0; j < 4; j++) acc[i][j] = floatx4{0.f, 0.f, 0.f, 0.f};

  for (int k0 = 0; k0 < K; k0 += 64) {
    __syncthreads();
#pragma unroll
    for (int i = 0; i < 4; i++) {
      int e = i * 256 + tid;
      int row = e >> 3, grp = e & 7;
      int gg = grp ^ (row & 7);
      async_copy16(A + (size_t)(m0 + row) * K + k0 + gg * 8, As + e * 8);
    }
#pragma unroll
    for (int i = 0; i < 4; i++) {
      int e = i * 256 + tid;
      int row = e >> 3, grp = e & 7;
      int gg = grp ^ (row & 7);
      async_copy16(Bt + (size_t)(n0 + row) * K + k0 + gg * 8, Bs + e * 8);
    }
    __syncthreads();
#pragma unroll
    for (int ks = 0; ks < 2; ks++) {
      bf16x8 af[4], bfr[4];
      int grp = ks * 4 + quad;
#pragma unroll
      for (int mi = 0; mi < 4; mi++) {
        int row = wm + mi * 16 + l16;
        af[mi] = *(const bf16x8*)(As + row * 64 + ((grp ^ (row & 7)) << 3));
      }
#pragma unroll
      for (int ni = 0; ni < 4; ni++) {
        int row = wn + ni * 16 + l16;
        bfr[ni] = *(const bf16x8*)(Bs + row * 64 + ((grp ^ (row & 7)) << 3));
      }
#pragma unroll
      for (int mi = 0; mi < 4; mi++)
#pragma unroll
        for (int ni = 0; ni < 4; ni++)
          acc[mi][ni] = __builtin_amdgcn_mfma_f32_16x16x32_bf16(af[mi], bfr[ni], acc[mi][ni], 0, 0, 0);
    }
  }
  // epilogue: C row = quad*4+reg (+16*mi), col = lane&15 (+16*ni)  [m89/m91 layout]
#pragma unroll
  for (int mi = 0; mi < 4; mi++) {
#pragma unroll
    for (int r = 0; r < 4; r++) {
      int row = m0 + wm + mi * 16 + quad * 4 + r;
      size_t base = (size_t)row * N + n0 + wn;
#pragma unroll
      for (int ni = 0; ni < 4; ni++)
        C[base + ni * 16 + l16] = (OUT_T)acc[mi][ni][r];
    }
  }
}

// ---------------------------------------------------------------------------
// RoPE + scatter: qkv (4096, 3072) bf16 -> Qb (B,NH,T,HD) scaled+roped,
//                 Kb (B,NKV,T,HD) roped.  One thread per (row, head, j<64).
// Q scale = 1/sqrt(128) * log2(e)  (flash softmax runs in exp2 domain)
__global__ void rope_scatter(const bf16_t* __restrict__ qkv,
                             bf16_t* __restrict__ Qb, bf16_t* __restrict__ Kb) {
  int g = blockIdx.x * 256 + threadIdx.x;
  int j = g & 63;
  int rest = g >> 6;
  int head = rest % (NH_ + NKV_);
  int row  = rest / (NH_ + NKV_);     // b*T + t
  int t = row & (T_ - 1);
  int b = row >> 11;                  // T_ = 2048
  const bf16_t* src = qkv + (size_t)row * NQKV;
  // inv_freq = 10000^(-j/64) = exp(-j * ln(10000)/64)
  float ang = (float)t * expf(-0.14391156816f * (float)j);
  float sn, cs;
  sincosf(ang, &sn, &cs);
  if (head < NH_) {
    float x0 = (float)src[head * HD_ + j];
    float x1 = (float)src[head * HD_ + 64 + j];
    const float scale = 0.12751651541057752f;  // 1/sqrt(128)*log2(e)
    bf16_t* dst = Qb + ((size_t)(b * NH_ + head) * T_ + t) * HD_;
    dst[j]      = (bf16_t)((x0 * cs - x1 * sn) * scale);
    dst[j + 64] = (bf16_t)((x1 * cs + x0 * sn) * scale);
  } else {
    int kvh = head - NH_;
    float x0 = (float)src[NH_ * HD_ + kvh * HD_ + j];
    float x1 = (float)src[NH_ * HD_ + kvh * HD_ + 64 + j];
    bf16_t* dst = Kb + ((size_t)(b * NKV_ + kvh) * T_ + t) * HD_;
    dst[j]      = (bf16_t)(x0 * cs - x1 * sn);
    dst[j + 64] = (bf16_t)(x1 * cs + x0 * sn);
  }
}

// ---------------------------------------------------------------------------
// V transpose: qkv V-slice (b,t,kv,d) -> Vt (B,NKV,HD,T)
__global__ void v_transpose(const bf16_t* __restrict__ qkv, bf16_t* __restrict__ Vt) {
  __shared__ float tile[32][33];
  int t0 = blockIdx.x * 32, d0 = blockIdx.y * 32;
  int bk = blockIdx.z;
  int b = bk / NKV_, kvh = bk % NKV_;
  int tx = threadIdx.x, ty = threadIdx.y;
#pragma unroll
  for (int r = 0; r < 4; r++) {
    int t = t0 + ty + r * 8;
    tile[ty + r*8][tx] =
        (float)qkv[(size_t)(b * T_ + t) * NQKV + (NH_ + NKV_) * HD_ + kvh * HD_ + d0 + tx];
  }
  __syncthreads();
#pragma unroll
  for (int r = 0; r < 4; r++) {
    int d = d0 + ty + r * 8;
    Vt[((size_t)(b * NKV_ + kvh) * HD_ + d) * T_ + t0 + tx] = (bf16_t)tile[tx][ty + r*8];
  }
}

// ---------------------------------------------------------------------------
// Flash attention v4: S^T formulation.
// mfma(kf, qf) -> S^T = K Q^T: each lane's 16 S-values all belong to ONE q-row
// (col = l16), so softmax row-reductions are 15 in-lane ops + 2 shuffles
// (xor16/xor32 across quads) instead of 4x(4+4) = 32 shuffles.  P^T goes to
// LDS as 4x ds_write_b64; PV computes O^T = V^T P^T where Vs (d,key) is
// already the perfect A-operand and P^T rows (q) are the B-operand.
// BQ=64/block, BK=64, double-buffered K/V staging, heavy-first order,
// exp2-domain softmax (scale*log2e folded into Q).
__global__ __launch_bounds__(256, 2)
void flash_attn(const bf16_t* __restrict__ Qb, const bf16_t* __restrict__ Kb,
                const bf16_t* __restrict__ Vt, bf16_t* __restrict__ Ob) {
  __shared__ __align__(16) bf16_t Ks[2][64 * 128];   // (key, d), swizzle grp^(row&15)
  __shared__ __align__(16) bf16_t Vs[2][128 * 64];   // (d, key), swizzle grp^(row&7)
  __shared__ __align__(16) bf16_t Ps[4][16 * 72];    // wave-private P^T: [q][key], +8 pad

  const int tid = threadIdx.x;
  const int wave = tid >> 6, lane = tid & 63;
  const int quad = lane >> 4, l16 = lane & 15;
  const int nQT = T_ / 64;  // 32
  const int bid = blockIdx.x;
  const int bh = bid % (B_ * NH_);
  const int qt = (nQT - 1) - (bid / (B_ * NH_));   // heavy-first
  const int h = bh % NH_;
  const int b = bh / NH_;
  const int kv = h >> 2;    // GQA: n_rep = 4

  const bf16_t* qbase = Qb + ((size_t)(b * NH_ + h) * T_ + qt * 64) * HD_;
  const bf16_t* kbase = Kb + ((size_t)(b * NKV_ + kv) * T_) * HD_;
  const bf16_t* vbase = Vt + ((size_t)(b * NKV_ + kv) * HD_) * T_;

  // stage key tile kt into buffer bufi (K: 64 keys x 128 d; V^T: 128 d x 64 keys)
  auto stage = [&](int kt, int bufi) {
#pragma unroll
    for (int i = 0; i < 4; i++) {
      int e = i * 256 + tid;
      int row = e >> 4, grp = e & 15;
      int gg = grp ^ (row & 15);
      async_copy16(kbase + (size_t)(kt * 64 + row) * HD_ + gg * 8, &Ks[bufi][e * 8]);
    }
#pragma unroll
    for (int i = 0; i < 4; i++) {
      int e = i * 256 + tid;
      int row = e >> 3, grp = e & 7;
      int gg = grp ^ (row & 7);
      async_copy16(vbase + (size_t)row * T_ + kt * 64 + gg * 8, &Vs[bufi][e * 8]);
    }
  };

  stage(0, 0);  // prefetch first tile before anything else

  // Q fragments (B-operand now; same register layout as A): lane n=l16 -> q row,
  // holds d = ks*32 + quad*8 + j.
  bf16x8 qf[4];
  {
    const bf16_t* qptr = qbase + (wave * 16 + l16) * HD_;
#pragma unroll
    for (int ks = 0; ks < 4; ks++)
      qf[ks] = *(const bf16x8*)(qptr + ks * 32 + quad * 8);
  }

  // O^T accumulators: o[dt][r] = O^T[d = dt*16+quad*4+r][q = l16]
  floatx4 o[8];
#pragma unroll
  for (int i = 0; i < 8; i++) o[i] = floatx4{0.f, 0.f, 0.f, 0.f};
  float m_s = -1e30f, l_s = 0.f;  // per-lane: this lane's q-row state

  for (int kt = 0; kt <= qt; kt++) {
    const int bufi = kt & 1;
    // barrier: (a) drains vmcnt -> staging of THIS tile (issued last iter) done;
    // (b) all waves finished compute on the buffer we are about to overwrite.
    __syncthreads();
    if (kt < qt) stage(kt + 1, bufi ^ 1);  // prefetch next tile (other buffer)

    // S^T = K Q^T : s[nt][r] = S^T[key = nt*16+quad*4+r][q = l16]
    floatx4 s[4];
#pragma unroll
    for (int nt = 0; nt < 4; nt++) s[nt] = floatx4{0.f, 0.f, 0.f, 0.f};
#pragma unroll
    for (int ks = 0; ks < 4; ks++) {
      int grp = ks * 4 + quad;
#pragma unroll
      for (int nt = 0; nt < 4; nt++) {
        int row = nt * 16 + l16;
        bf16x8 kf = *(const bf16x8*)(&Ks[bufi][row * 128 + ((grp ^ (row & 15)) << 3)]);
        s[nt] = __builtin_amdgcn_mfma_f32_16x16x32_bf16(kf, qf[ks], s[nt], 0, 0, 0);
      }
    }

    // causal mask (only the diagonal tile needs it): key_local > q_local
    if (kt == qt) {
      int qlocal = wave * 16 + l16;
#pragma unroll
      for (int nt = 0; nt < 4; nt++)
#pragma unroll
        for (int r = 0; r < 4; r++) {
          int klocal = nt * 16 + quad * 4 + r;
          if (klocal > qlocal) s[nt][r] = -1e30f;
        }
    }

    // online softmax, exp2 domain. All 16 values in this lane share one q-row;
    // full 64-key reduction = in-lane tree + 2 cross-quad shuffles.
    float mx = fmaxf(fmaxf(s[0][0], s[0][1]), fmaxf(s[0][2], s[0][3]));
#pragma unroll
    for (int nt = 1; nt < 4; nt++)
      mx = fmaxf(mx, fmaxf(fmaxf(s[nt][0], s[nt][1]), fmaxf(s[nt][2], s[nt][3])));
    mx = fmaxf(mx, __shfl_xor(mx, 16, 64));
    mx = fmaxf(mx, __shfl_xor(mx, 32, 64));
    float mnew = fmaxf(m_s, mx);
    float alpha = __builtin_amdgcn_exp2f(m_s - mnew);
    m_s = mnew;
    float sum = 0.f;
#pragma unroll
    for (int nt = 0; nt < 4; nt++)
#pragma unroll
      for (int r = 0; r < 4; r++) {
        float p = __builtin_amdgcn_exp2f(s[nt][r] - mnew);
        s[nt][r] = p;
        sum += p;
      }
    sum += __shfl_xor(sum, 16, 64);
    sum += __shfl_xor(sum, 32, 64);
    l_s = l_s * alpha + sum;
#pragma unroll
    for (int dt = 0; dt < 8; dt++) o[dt] *= alpha;

    // P^T -> LDS: row q=l16, keys nt*16+quad*4..+3 packed as one 8B write
#pragma unroll
    for (int nt = 0; nt < 4; nt++) {
      bf16x4 p4;
#pragma unroll
      for (int r = 0; r < 4; r++) p4[r] = (bf16_t)s[nt][r];
      *(bf16x4*)(&Ps[wave][l16 * 72 + nt * 16 + quad * 4]) = p4;
    }

    // O^T += V^T P^T : A = Vs (d,key) as stored; B = P^T rows (8 keys/lane)
#pragma unroll
    for (int ks = 0; ks < 2; ks++) {
      bf16x8 pf = *(const bf16x8*)(&Ps[wave][l16 * 72 + ks * 32 + quad * 8]);
      int grp = ks * 4 + quad;
#pragma unroll
      for (int dt = 0; dt < 8; dt++) {
        int row = dt * 16 + l16;
        bf16x8 vf = *(const bf16x8*)(&Vs[bufi][row * 64 + ((grp ^ (row & 7)) << 3)]);
        o[dt] = __builtin_amdgcn_mfma_f32_16x16x32_bf16(vf, pf, o[dt], 0, 0, 0);
      }
    }
  }

  // epilogue: lane owns q-row qg = wrow0 + l16; d = dt*16+quad*4+r.
  // Pack 4 consecutive d as 8B stores.
  {
    int qg = qt * 64 + wave * 16 + l16;
    float inv_l = 1.f / l_s;
    size_t base = ((size_t)(b * T_) + qg) * D_ + h * HD_;
#pragma unroll
    for (int dt = 0; dt < 8; dt++) {
      bf16x4 w;
#pragma unroll
      for (int r = 0; r < 4; r++) w[r] = (bf16_t)(o[dt][r] * inv_l);
      *(bf16x4*)(Ob + base + dt * 16 + quad * 4) = w;
    }
  }
}

// ---------------------------------------------------------------------------
extern "C" void kernel_launch(void* const* d_in, const int* in_sizes, int n_in,
                              void* d_out, int out_size, void* d_ws, size_t ws_size,
                              hipStream_t stream) {
  const float* x  = (const float*)d_in[0];
  const float* wq = (const float*)d_in[1];
  const float* wk = (const float*)d_in[2];
  const float* wv = (const float*)d_in[3];
  const float* wo = (const float*)d_in[4];
  float* out = (float*)d_out;

  // workspace layout (bf16 elems); attn output aliases x_bf (x_bf dead after GEMM1)
  bf16_t* x_bf   = (bf16_t*)d_ws;                          // 4096*2048
  bf16_t* attn_o = x_bf;                                   // alias
  bf16_t* wqkv_t = x_bf + (size_t)MROWS * D_;              // 3072*2048
  bf16_t* wo_t   = wqkv_t + (size_t)NQKV * D_;             // 2048*2048
  bf16_t* qkv    = wo_t + (size_t)D_ * D_;                 // 4096*3072
  bf16_t* Qb     = qkv + (size_t)MROWS * NQKV;             // 2*16*2048*128
  bf16_t* Kb     = Qb + (size_t)B_ * NH_ * T_ * HD_;       // 2*4*2048*128
  bf16_t* Vt     = Kb + (size_t)B_ * NKV_ * T_ * HD_;      // 2*4*128*2048

  // 1. casts / weight transposes
  cast_f32_bf16<<<(MROWS * D_) / (256 * 8), 256, 0, stream>>>(x, x_bf, MROWS * D_);
  transpose_cast<<<dim3(64, 64), dim3(32, 8), 0, stream>>>(wq, wqkv_t, D_, 2048);
  transpose_cast<<<dim3(16, 64), dim3(32, 8), 0, stream>>>(wk, wqkv_t + (size_t)2048 * D_, D_, 512);
  transpose_cast<<<dim3(16, 64), dim3(32, 8), 0, stream>>>(wv, wqkv_t + (size_t)2560 * D_, D_, 512);
  transpose_cast<<<dim3(64, 64), dim3(32, 8), 0, stream>>>(wo, wo_t, D_, 2048);

  // 2. fused QKV projection: (4096,2048) x (2048,3072) -> bf16
  gemm_bt<bf16_t><<<(MROWS / 128) * (NQKV / 128), 256, 0, stream>>>(
      x_bf, wqkv_t, qkv, MROWS, NQKV, D_);

  // 3. RoPE + GQA scatter + V transpose
  rope_scatter<<<(MROWS * (NH_ + NKV_) * 64) / 256, 256, 0, stream>>>(qkv, Qb, Kb);
  v_transpose<<<dim3(T_ / 32, HD_ / 32, B_ * NKV_), dim3(32, 8), 0, stream>>>(qkv, Vt);

  // 4. causal flash attention: S^T formulation, double-buffered, heavy-first
  flash_attn<<<B_ * NH_ * (T_ / 64), 256, 0, stream>>>(Qb, Kb, Vt, attn_o);

  // 5. output projection: (4096,2048) x (2048,2048) -> fp32
  gemm_bt<float><<<(MROWS / 128) * (D_ / 128), 256, 0, stream>>>(
      attn_o, wo_t, out, MROWS, D_, D_);
}